// Round 2
// baseline (72.846 us; speedup 1.0000x reference)
//
#include <hip/hip_runtime.h>

#define ALPHA 0.2f

constexpr int N = 1024;
constexpr int F = 64;

// ---------------- k1: e1 = h@(W@a1), e2 = h@(W@a2) ----------------
// 256 blocks x 256 threads; per block: redundant tiny w1/w2, then 4 rows.
// (verbatim round-0 kernel, known-good, ~2 us)
__global__ __launch_bounds__(256) void k1e(const float* __restrict__ h,
                                           const float* __restrict__ W,
                                           const float* __restrict__ a,
                                           float* __restrict__ e1,
                                           float* __restrict__ e2) {
    const int t = threadIdx.x;
    __shared__ float w1s[F], w2s[F];

    {
        const int f = t >> 2;
        const int c0 = (t & 3) * 16;
        float s1 = 0.f, s2 = 0.f;
        #pragma unroll
        for (int q = 0; q < 4; ++q) {
            const float4 wv  = *(const float4*)&W[f * F + c0 + q * 4];
            const float4 a1v = *(const float4*)&a[c0 + q * 4];
            const float4 a2v = *(const float4*)&a[F + c0 + q * 4];
            s1 += wv.x*a1v.x + wv.y*a1v.y + wv.z*a1v.z + wv.w*a1v.w;
            s2 += wv.x*a2v.x + wv.y*a2v.y + wv.z*a2v.z + wv.w*a2v.w;
        }
        s1 += __shfl_down(s1, 2); s1 += __shfl_down(s1, 1);
        s2 += __shfl_down(s2, 2); s2 += __shfl_down(s2, 1);
        if ((t & 3) == 0) { w1s[f] = s1; w2s[f] = s2; }
    }
    __syncthreads();

    const int wave = t >> 6;
    const int lane = t & 63;
    const int i = blockIdx.x * 4 + wave;
    const float hv = h[(size_t)i * F + lane];
    float v1 = hv * w1s[lane];
    float v2 = hv * w2s[lane];
    #pragma unroll
    for (int off = 32; off > 0; off >>= 1) {
        v1 += __shfl_down(v1, off);
        v2 += __shfl_down(v2, off);
    }
    if (lane == 0) {
        e1[i] = v1;
        e2[i] = v2;
    }
}

// ---------------- k2: 2-D partial sweep ----------------
// grid 256 = ig(64) x jg(4); 1024 threads = 16 waves.
// Block covers rows [16*ig, +16) x cols [256*jg, +256).
// Wave w owns the 16-column slice [j0 + 16w, +16).
// Per-block h traffic: 256 rows x 256 B = 64 KB (8x less than round 1).
// Writes partial u[16][64] and partial den[16] to workspace.
__global__ __launch_bounds__(1024) void k2p(const int* __restrict__ adj,
                                            const float* __restrict__ h,
                                            const float* __restrict__ e1,
                                            const float* __restrict__ e2,
                                            float* __restrict__ wsu,
                                            float* __restrict__ wsd) {
    const int t = threadIdx.x;
    const int wave = t >> 6;
    const int lane = t & 63;
    const int ig = blockIdx.x >> 2;
    const int jg = blockIdx.x & 3;
    const int i0 = ig * 16;
    const int j0 = jg * 256;

    __shared__ float e1s[16];
    __shared__ float e2s[256];            // 1 KB
    __shared__ float pws[16][16][16];     // 16 KB  [wave][r][jj] - same-wave use only
    __shared__ float accs[16][16][64];    // 64 KB  [wave][r][f]
    __shared__ float dens[16][16];        // 1 KB   [wave][r]

    // lane -> (r, hi): computes p for row r, cols jj = hi*4..hi*4+3
    const int r  = lane & 15;
    const int hi = lane >> 4;

    // prefetch adj (issued before any LDS wait); read exactly once grid-wide
    const int4 av = *(const int4*)&adj[(size_t)(i0 + r) * N + j0 + wave * 16 + hi * 4];

    if (t < 256) e2s[t] = e2[j0 + t];
    if (t < 16)  e1s[t] = e1[i0 + t];
    __syncthreads();                      // B1: e1s/e2s ready

    // ---- p-values: 4 per lane; per-row partial denominator via 4-lane reduce ----
    {
        const float e1r = e1s[r];
        const int jb = wave * 16 + hi * 4;
        float4 pv; float s;
        s = e1r + e2s[jb + 0]; s = (s > 0.f) ? s : ALPHA * s; pv.x = (av.x > 0) ? __expf(s) : 0.f;
        s = e1r + e2s[jb + 1]; s = (s > 0.f) ? s : ALPHA * s; pv.y = (av.y > 0) ? __expf(s) : 0.f;
        s = e1r + e2s[jb + 2]; s = (s > 0.f) ? s : ALPHA * s; pv.z = (av.z > 0) ? __expf(s) : 0.f;
        s = e1r + e2s[jb + 3]; s = (s > 0.f) ? s : ALPHA * s; pv.w = (av.w > 0) ? __expf(s) : 0.f;
        *(float4*)&pws[wave][r][hi * 4] = pv;
        float d = (pv.x + pv.y) + (pv.z + pv.w);
        d += __shfl_down(d, 32);          // lanes sharing r: {r, r+16, r+32, r+48}
        d += __shfl_down(d, 16);
        if (lane < 16) dens[wave][lane] = d;
    }
    // pws consumed only by the producing wave: lgkmcnt drain, no barrier
    asm volatile("s_waitcnt lgkmcnt(0)" ::: "memory");

    // ---- partial u: wave sums its 16 j's; lane = f; 256 FMA/thread ----
    {
        float u[16];
        #pragma unroll
        for (int rr = 0; rr < 16; ++rr) u[rr] = 0.f;
        const float* hb = h + (size_t)(j0 + wave * 16) * F + lane;
        #pragma unroll
        for (int g4 = 0; g4 < 4; ++g4) {
            float hv[4];
            #pragma unroll
            for (int q = 0; q < 4; ++q)
                hv[q] = hb[(size_t)(g4 * 4 + q) * F];          // coalesced 256B, L2-hot
            #pragma unroll
            for (int rg = 0; rg < 4; ++rg) {
                const float4 p0 = *(const float4*)&pws[wave][rg * 4 + 0][g4 * 4];  // uniform: broadcast
                const float4 p1 = *(const float4*)&pws[wave][rg * 4 + 1][g4 * 4];
                const float4 p2 = *(const float4*)&pws[wave][rg * 4 + 2][g4 * 4];
                const float4 p3 = *(const float4*)&pws[wave][rg * 4 + 3][g4 * 4];
                #pragma unroll
                for (int q = 0; q < 4; ++q) {
                    u[rg * 4 + 0] += (&p0.x)[q] * hv[q];
                    u[rg * 4 + 1] += (&p1.x)[q] * hv[q];
                    u[rg * 4 + 2] += (&p2.x)[q] * hv[q];
                    u[rg * 4 + 3] += (&p3.x)[q] * hv[q];
                }
            }
        }
        #pragma unroll
        for (int rr = 0; rr < 16; ++rr) accs[wave][rr][lane] = u[rr];  // 2-way alias: free
    }
    __syncthreads();                      // B2: accs + dens visible

    // ---- cross-wave reduce -> workspace partials ----
    {
        const int r2 = t >> 6;            // wave w reduces row r2 = w
        const int f  = t & 63;
        float su = 0.f;
        #pragma unroll
        for (int w = 0; w < 16; ++w) su += accs[w][r2][f];
        wsu[(size_t)((i0 + r2) * 4 + jg) * 64 + f] = su;   // coalesced 256B/wave
        if (t < 16) {
            float d = 0.f;
            #pragma unroll
            for (int w = 0; w < 16; ++w) d += dens[w][t];
            wsd[(i0 + t) * 4 + jg] = d;
        }
    }
}

// ---------------- k3: combine partials, normalize, @W, elu ----------------
// 256 blocks x 256 threads; block handles 4 output rows.
__global__ __launch_bounds__(256) void k3f(const float* __restrict__ wsu,
                                           const float* __restrict__ wsd,
                                           const float* __restrict__ W,
                                           float* __restrict__ out) {
    const int t = threadIdx.x;
    const int rr = t >> 6;
    const int g  = t & 63;
    const int i  = blockIdx.x * 4 + rr;
    __shared__ float us[4][F];

    float su = 0.f;
    #pragma unroll
    for (int jg = 0; jg < 4; ++jg)
        su += wsu[(size_t)(i * 4 + jg) * 64 + g];          // coalesced
    const float d = wsd[i * 4 + 0] + wsd[i * 4 + 1] + wsd[i * 4 + 2] + wsd[i * 4 + 3];
    us[rr][g] = su / d;
    __syncthreads();

    float acc = 0.f;
    #pragma unroll
    for (int f = 0; f < F; ++f)
        acc += us[rr][f] * W[f * F + g];                   // us broadcast; W coalesced
    out[(size_t)i * F + g] = (acc > 0.f) ? acc : expm1f(acc);
}

extern "C" void kernel_launch(void* const* d_in, const int* in_sizes, int n_in,
                              void* d_out, int out_size, void* d_ws, size_t ws_size,
                              hipStream_t stream) {
    const float* h   = (const float*)d_in[0];
    const int*   adj = (const int*)d_in[1];
    const float* W   = (const float*)d_in[2];
    const float* a   = (const float*)d_in[3];
    float* out       = (float*)d_out;

    float* ws  = (float*)d_ws;
    float* e1  = ws;                    // 1024
    float* e2  = ws + N;                // 1024
    float* wsu = ws + 2 * N;            // 1024*4*64 = 262144
    float* wsd = ws + 2 * N + N * 4 * F;// 4096

    k1e<<<256, 256, 0, stream>>>(h, W, a, e1, e2);
    k2p<<<256, 1024, 0, stream>>>(adj, h, e1, e2, wsu, wsd);
    k3f<<<256, 256, 0, stream>>>(wsu, wsd, W, out);
}